// Round 1
// baseline (614.817 us; speedup 1.0000x reference)
//
#include <hip/hip_runtime.h>

#define N_ 32
#define C_ 128
#define K_ 64
#define S_ 16384
#define TS 32
#define CHUNK 1024
#define NCHUNK (S_/CHUNK)   // 16 chunks per image -> 512 blocks
#define WSTRIDE 132         // 128 + 4 pad (keeps 16B alignment, breaks pow2 banks)
#define LSTRIDE 68          // 64 + 4 pad
#define EPS 1e-12f

// ---------------------------------------------------------------------------
// Kernel 1: fused  logits = W @ x_tile  -> softmax over K -> vlad += a @ x^T
// Grid: N_ * NCHUNK blocks, 256 threads. x read exactly once from HBM.
// ---------------------------------------------------------------------------
__global__ __launch_bounds__(256, 2) void vlad_main(
    const float* __restrict__ x, const float* __restrict__ w,
    float* __restrict__ vlad_acc, float* __restrict__ asum_g) {
  __shared__ __align__(16) float sW[K_ * WSTRIDE];   // conv_w [k][c]
  __shared__ __align__(16) float sX[TS * WSTRIDE];   // x tile transposed [s][c]
  __shared__ __align__(16) float sL[TS * LSTRIDE];   // logits / soft-assign [s][k]

  const int tid = threadIdx.x;
  const int bid = blockIdx.x;
  const int n = bid >> 4;          // 16 chunks per n
  const int chunk = bid & 15;
  const int sbase = chunk * CHUNK;

  // load conv_w into LDS (coalesced)
  for (int idx = tid; idx < K_ * C_; idx += 256) {
    int k = idx >> 7, c = idx & 127;
    sW[k * WSTRIDE + c] = w[idx];
  }

  // persistent per-thread vlad accumulator: 4 k  x  8 c  (c = 4ct+j and 64+4ct+j)
  float acc[4][8];
#pragma unroll
  for (int i = 0; i < 4; i++)
#pragma unroll
    for (int j = 0; j < 8; j++) acc[i][j] = 0.f;
  float asum_acc = 0.f;

  // thread-role indices
  const int cA = tid & 127;  const int hA = tid >> 7;   // staging: c row, s half
  const int ktB = tid >> 4;  const int stB = tid & 15;  // logits: k-tile, s
  const int sC  = tid >> 3;  const int kqC = tid & 7;   // softmax: s, k-oct
  const int ktD = tid >> 4;  const int ctD = tid & 15;  // vlad: k-tile, c-tile
  const int kE  = tid >> 2;  const int pE  = tid & 3;   // asum: k, s-part

  const float* xn = x + ((size_t)n * C_ + cA) * S_;

  __syncthreads();

  for (int t = 0; t < CHUNK / TS; t++) {
    const int s0 = sbase + t * TS;

    // ---- Phase A: stage x[n, :, s0:s0+32] transposed into sX[s][c] ----
    {
      const float* p = xn + s0 + hA * 16;          // 64B-aligned
      float4 v0 = *(const float4*)(p + 0);
      float4 v1 = *(const float4*)(p + 4);
      float4 v2 = *(const float4*)(p + 8);
      float4 v3 = *(const float4*)(p + 12);
      float vv[16] = {v0.x,v0.y,v0.z,v0.w, v1.x,v1.y,v1.z,v1.w,
                      v2.x,v2.y,v2.z,v2.w, v3.x,v3.y,v3.z,v3.w};
      const int sb = hA * 16;
#pragma unroll
      for (int u = 0; u < 16; u++) sX[(sb + u) * WSTRIDE + cA] = vv[u];
    }
    __syncthreads();

    // ---- Phase B: logits[k][s] = sum_c W[k][c] * x[s][c], 4k x 2s per thread ----
    {
      float l[4][2] = {{0.f,0.f},{0.f,0.f},{0.f,0.f},{0.f,0.f}};
#pragma unroll 4
      for (int cq = 0; cq < 32; cq++) {
        float4 x0 = *(const float4*)&sX[stB * WSTRIDE + cq * 4];
        float4 x1 = *(const float4*)&sX[(stB + 16) * WSTRIDE + cq * 4];
#pragma unroll
        for (int i = 0; i < 4; i++) {
          float4 wv = *(const float4*)&sW[(ktB * 4 + i) * WSTRIDE + cq * 4];
          l[i][0] += wv.x*x0.x + wv.y*x0.y + wv.z*x0.z + wv.w*x0.w;
          l[i][1] += wv.x*x1.x + wv.y*x1.y + wv.z*x1.z + wv.w*x1.w;
        }
      }
      float4 o0 = make_float4(l[0][0], l[1][0], l[2][0], l[3][0]);
      float4 o1 = make_float4(l[0][1], l[1][1], l[2][1], l[3][1]);
      *(float4*)&sL[stB * LSTRIDE + ktB * 4] = o0;
      *(float4*)&sL[(stB + 16) * LSTRIDE + ktB * 4] = o1;
    }
    __syncthreads();

    // ---- Phase C: softmax over k (64) per s; 8 k's per thread, shfl over 8 lanes ----
    {
      float4 va = *(const float4*)&sL[sC * LSTRIDE + kqC * 8];
      float4 vb = *(const float4*)&sL[sC * LSTRIDE + kqC * 8 + 4];
      float m = fmaxf(fmaxf(fmaxf(va.x, va.y), fmaxf(va.z, va.w)),
                      fmaxf(fmaxf(vb.x, vb.y), fmaxf(vb.z, vb.w)));
      m = fmaxf(m, __shfl_xor(m, 1));
      m = fmaxf(m, __shfl_xor(m, 2));
      m = fmaxf(m, __shfl_xor(m, 4));
      va.x = __expf(va.x - m); va.y = __expf(va.y - m);
      va.z = __expf(va.z - m); va.w = __expf(va.w - m);
      vb.x = __expf(vb.x - m); vb.y = __expf(vb.y - m);
      vb.z = __expf(vb.z - m); vb.w = __expf(vb.w - m);
      float sum = va.x + va.y + va.z + va.w + vb.x + vb.y + vb.z + vb.w;
      sum += __shfl_xor(sum, 1);
      sum += __shfl_xor(sum, 2);
      sum += __shfl_xor(sum, 4);
      float inv = 1.f / sum;
      va.x *= inv; va.y *= inv; va.z *= inv; va.w *= inv;
      vb.x *= inv; vb.y *= inv; vb.z *= inv; vb.w *= inv;
      *(float4*)&sL[sC * LSTRIDE + kqC * 8] = va;
      *(float4*)&sL[sC * LSTRIDE + kqC * 8 + 4] = vb;
    }
    __syncthreads();

    // ---- Phase D: vlad[k][c] += a[s][k] * x[s][c]  (4k x 8c per thread) ----
    {
#pragma unroll 4
      for (int s = 0; s < TS; s++) {
        float4 a4 = *(const float4*)&sL[s * LSTRIDE + ktD * 4];
        float4 xa = *(const float4*)&sX[s * WSTRIDE + ctD * 4];
        float4 xb = *(const float4*)&sX[s * WSTRIDE + ctD * 4 + 64];
        float aa[4] = {a4.x, a4.y, a4.z, a4.w};
        float xc[8] = {xa.x, xa.y, xa.z, xa.w, xb.x, xb.y, xb.z, xb.w};
#pragma unroll
        for (int i = 0; i < 4; i++)
#pragma unroll
          for (int j = 0; j < 8; j++) acc[i][j] += aa[i] * xc[j];
      }
      // ---- Phase E: per-tile a-sum over s (reads only; no barrier vs D) ----
      float p = 0.f;
#pragma unroll
      for (int i = 0; i < 8; i++) p += sL[(pE * 8 + i) * LSTRIDE + kE];
      p += __shfl_xor(p, 1);
      p += __shfl_xor(p, 2);
      if (pE == 0) asum_acc += p;
    }
    __syncthreads();
  }

  // ---- epilogue: accumulate partials to global workspace ----
  float* vbase = vlad_acc + (size_t)n * K_ * C_;
#pragma unroll
  for (int i = 0; i < 4; i++) {
    int k = ktD * 4 + i;
#pragma unroll
    for (int j = 0; j < 8; j++) {
      int c = (j < 4) ? (ctD * 4 + j) : (64 + ctD * 4 + (j - 4));
      atomicAdd(vbase + k * C_ + c, acc[i][j]);
    }
  }
  if (pE == 0) atomicAdd(asum_g + n * K_ + kE, asum_acc);
}

// ---------------------------------------------------------------------------
// Kernel 2: per-(n,k) subtract asum*centroid, intra-normalize over c (in place),
// accumulate global norm^2 contribution.
// ---------------------------------------------------------------------------
__global__ __launch_bounds__(128) void vlad_intra(
    float* __restrict__ vlad_acc, const float* __restrict__ asum_g,
    const float* __restrict__ cent, float* __restrict__ gnorm) {
  const int bid = blockIdx.x;
  const int n = bid >> 6, k = bid & 63;
  const int c = threadIdx.x;
  const size_t base = ((size_t)(n * K_ + k)) * C_;
  float a = asum_g[n * K_ + k];
  float v = vlad_acc[base + c] - a * cent[k * C_ + c];
  float ss = v * v;
  ss += __shfl_xor(ss, 1);  ss += __shfl_xor(ss, 2);  ss += __shfl_xor(ss, 4);
  ss += __shfl_xor(ss, 8);  ss += __shfl_xor(ss, 16); ss += __shfl_xor(ss, 32);
  __shared__ float red[2];
  if ((threadIdx.x & 63) == 0) red[threadIdx.x >> 6] = ss;
  __syncthreads();
  float total = red[0] + red[1];
  float nrm = fmaxf(sqrtf(total), EPS);
  vlad_acc[base + c] = v / nrm;
  if (threadIdx.x == 0) atomicAdd(gnorm + n, total / (nrm * nrm));
}

// ---------------------------------------------------------------------------
// Kernel 3: global L2 normalize per n, write output.
// ---------------------------------------------------------------------------
__global__ __launch_bounds__(256) void vlad_final(
    const float* __restrict__ vlad_acc, const float* __restrict__ gnorm,
    float* __restrict__ out) {
  const int idx = blockIdx.x * 256 + threadIdx.x;
  if (idx >= N_ * K_ * C_) return;
  float g = gnorm[idx >> 13];  // / (K_*C_) = 8192
  out[idx] = vlad_acc[idx] / fmaxf(sqrtf(g), EPS);
}

extern "C" void kernel_launch(void* const* d_in, const int* in_sizes, int n_in,
                              void* d_out, int out_size, void* d_ws, size_t ws_size,
                              hipStream_t stream) {
  const float* x    = (const float*)d_in[0];   // [32,128,128,128]
  const float* w    = (const float*)d_in[1];   // [64,128]
  const float* cent = (const float*)d_in[2];   // [64,128]
  float* out = (float*)d_out;                  // [32, 8192]

  float* vlad_acc = (float*)d_ws;              // N*K*C floats
  float* asum_g   = vlad_acc + N_ * K_ * C_;   // N*K floats
  float* gnorm    = asum_g + N_ * K_;          // N floats

  const size_t zero_bytes = (size_t)(N_ * K_ * C_ + N_ * K_ + N_) * sizeof(float);
  hipMemsetAsync(d_ws, 0, zero_bytes, stream);

  vlad_main<<<dim3(N_ * NCHUNK), dim3(256), 0, stream>>>(x, w, vlad_acc, asum_g);
  vlad_intra<<<dim3(N_ * K_), dim3(128), 0, stream>>>(vlad_acc, asum_g, cent, gnorm);
  vlad_final<<<dim3((N_ * K_ * C_ + 255) / 256), dim3(256), 0, stream>>>(vlad_acc, gnorm, out);
}

// Round 2
// 496.109 us; speedup vs baseline: 1.2393x; 1.2393x over previous
//
#include <hip/hip_runtime.h>
#include <hip/hip_bf16.h>

#define N_ 32
#define C_ 128
#define K_ 64
#define S_ 16384
#define TS 32                // s-positions per inner tile
#define CHUNK 1024
#define NCHUNK (S_/CHUNK)    // 16 chunks/image -> 512 blocks
#define CP 136               // x^T LDS stride (bf16 elems; 272B, 16B-aligned)
#define LP 68                // logits LDS stride (fp32)
#define SP 40                // probs LDS stride (bf16 elems; 80B, 16B-aligned)
#define EPS 1e-12f

typedef __attribute__((ext_vector_type(8))) short short8;
typedef __attribute__((ext_vector_type(4))) float floatx4;

__device__ inline unsigned short bfraw(float v) {
  return __builtin_bit_cast(unsigned short, __float2bfloat16(v));
}
__device__ inline float bff(unsigned short u) {
  union { unsigned int i; float f; } c; c.i = ((unsigned int)u) << 16; return c.f;
}

// ---------------------------------------------------------------------------
// Fused: logits = W@x (MFMA, split-bf16) -> softmax over k -> vlad += a@x^T
// (MFMA, split-bf16). Grid: 512 blocks x 256 threads (4 waves).
// Wave w owns: GEMM1 kc-tile w (W frags in regs); GEMM2 c-tiles {2w,2w+1}.
// ---------------------------------------------------------------------------
__global__ __launch_bounds__(256, 2) void vlad_main(
    const float* __restrict__ x, const float* __restrict__ w,
    float* __restrict__ vlad_acc, float* __restrict__ asum_g) {
  __shared__ unsigned short sXTh[TS * CP];   // x^T tile hi [s][c]
  __shared__ unsigned short sXTl[TS * CP];   // x^T tile lo
  __shared__ float sLog[TS * LP];            // logits [s][kc]
  __shared__ unsigned short sPh[K_ * SP];    // probs hi [kc][s]
  __shared__ unsigned short sPl[K_ * SP];    // probs lo

  const int tid = threadIdx.x;
  const int lane = tid & 63;
  const int wv = tid >> 6;
  const int n = blockIdx.x >> 4;
  const int chunk = blockIdx.x & 15;
  const int sbase = chunk * CHUNK;

  const int lm = lane & 15;   // mfma m/n lane index
  const int lq = lane >> 4;   // mfma quad
  const int kb = lq * 8;      // k-offset of this lane's frag elems

  // --- GEMM1 B-fragments: W[kc][c] for kc-tile wv, kept in registers ---
  short8 Wh[4], Wl[4];
  {
    const float* wp = w + (wv * 16 + lm) * C_;
#pragma unroll
    for (int ks = 0; ks < 4; ++ks) {
      const float* p = wp + ks * 32 + kb;
      float4 a = *(const float4*)p;
      float4 b = *(const float4*)(p + 4);
      float e[8] = {a.x, a.y, a.z, a.w, b.x, b.y, b.z, b.w};
#pragma unroll
      for (int j = 0; j < 8; ++j) {
        unsigned short h = bfraw(e[j]);
        Wh[ks][j] = (short)h;
        Wl[ks][j] = (short)bfraw(e[j] - bff(h));
      }
    }
  }

  floatx4 acc[2][4];   // vlad^T accumulators: c-tile ci, kc-tile kt
#pragma unroll
  for (int i = 0; i < 2; ++i)
#pragma unroll
    for (int j = 0; j < 4; ++j) acc[i][j] = (floatx4){0.f, 0.f, 0.f, 0.f};
  float accA[8];       // per-thread soft-assign sums (kc = octC + 8i)
#pragma unroll
  for (int i = 0; i < 8; ++i) accA[i] = 0.f;

  const int cA = tid & 127, hA = tid >> 7;          // staging roles
  const float* xstg = x + ((size_t)n * C_ + cA) * S_ + sbase + hA * 16;
  const int sC = tid >> 3, octC = tid & 7;          // softmax roles

  for (int t = 0; t < CHUNK / TS; ++t) {
    const int s0 = sbase + t * TS;

    // ---- Phase A: stage x^T tile (hi/lo bf16) into LDS ----
    {
      const float* p = xstg + t * TS;
      float4 v0 = *(const float4*)(p + 0);
      float4 v1 = *(const float4*)(p + 4);
      float4 v2 = *(const float4*)(p + 8);
      float4 v3 = *(const float4*)(p + 12);
      float vv[16] = {v0.x,v0.y,v0.z,v0.w, v1.x,v1.y,v1.z,v1.w,
                      v2.x,v2.y,v2.z,v2.w, v3.x,v3.y,v3.z,v3.w};
      const int sb = hA * 16;
#pragma unroll
      for (int u = 0; u < 16; ++u) {
        unsigned short h = bfraw(vv[u]);
        sXTh[(sb + u) * CP + cA] = h;
        sXTl[(sb + u) * CP + cA] = bfraw(vv[u] - bff(h));
      }
    }
    __syncthreads();

    // ---- Phase B: logits[s][kc] via MFMA (A = x^T from LDS, B = W regs) ----
#pragma unroll
    for (int st = 0; st < 2; ++st) {
      floatx4 D = {0.f, 0.f, 0.f, 0.f};
      const int srow = st * 16 + lm;
#pragma unroll
      for (int ks = 0; ks < 4; ++ks) {
        short8 Ah = *(const short8*)&sXTh[srow * CP + ks * 32 + kb];
        short8 Al = *(const short8*)&sXTl[srow * CP + ks * 32 + kb];
        D = __builtin_amdgcn_mfma_f32_16x16x32_bf16(Ah, Wh[ks], D, 0, 0, 0);
        D = __builtin_amdgcn_mfma_f32_16x16x32_bf16(Al, Wh[ks], D, 0, 0, 0);
        D = __builtin_amdgcn_mfma_f32_16x16x32_bf16(Ah, Wl[ks], D, 0, 0, 0);
      }
      const int sD = st * 16 + lq * 4;
      const int kcD = wv * 16 + lm;
#pragma unroll
      for (int r = 0; r < 4; ++r) sLog[(sD + r) * LP + kcD] = D[r];
    }
    __syncthreads();

    // ---- Phase C: softmax over kc per s (thread: s=tid>>3, kc=octC+8i) ----
    {
      float e[8];
      float m = -1e30f;
#pragma unroll
      for (int i = 0; i < 8; ++i) {
        e[i] = sLog[sC * LP + octC + 8 * i];
        m = fmaxf(m, e[i]);
      }
      m = fmaxf(m, __shfl_xor(m, 1));
      m = fmaxf(m, __shfl_xor(m, 2));
      m = fmaxf(m, __shfl_xor(m, 4));
      float sum = 0.f;
#pragma unroll
      for (int i = 0; i < 8; ++i) { e[i] = __expf(e[i] - m); sum += e[i]; }
      sum += __shfl_xor(sum, 1);
      sum += __shfl_xor(sum, 2);
      sum += __shfl_xor(sum, 4);
      float inv = 1.f / sum;
#pragma unroll
      for (int i = 0; i < 8; ++i) {
        float pr = e[i] * inv;
        accA[i] += pr;
        unsigned short h = bfraw(pr);
        sPh[(octC + 8 * i) * SP + sC] = h;
        sPl[(octC + 8 * i) * SP + sC] = bfraw(pr - bff(h));
      }
    }
    __syncthreads();

    // ---- Phase D: vlad^T[c][kc] += x[c][s]·a[kc][s] (A from global, L2-hot) ----
    {
      short8 Bh[4], Bl[4];
#pragma unroll
      for (int kt = 0; kt < 4; ++kt) {
        Bh[kt] = *(const short8*)&sPh[(kt * 16 + lm) * SP + kb];
        Bl[kt] = *(const short8*)&sPl[(kt * 16 + lm) * SP + kb];
      }
#pragma unroll
      for (int ci = 0; ci < 2; ++ci) {
        const int crow = (wv * 2 + ci) * 16 + lm;
        const float* xp = x + ((size_t)n * C_ + crow) * S_ + s0 + kb;
        float4 a = *(const float4*)xp;
        float4 b = *(const float4*)(xp + 4);
        float e[8] = {a.x, a.y, a.z, a.w, b.x, b.y, b.z, b.w};
        short8 Ah, Al;
#pragma unroll
        for (int j = 0; j < 8; ++j) {
          unsigned short h = bfraw(e[j]);
          Ah[j] = (short)h;
          Al[j] = (short)bfraw(e[j] - bff(h));
        }
#pragma unroll
        for (int kt = 0; kt < 4; ++kt) {
          acc[ci][kt] = __builtin_amdgcn_mfma_f32_16x16x32_bf16(Ah, Bh[kt], acc[ci][kt], 0, 0, 0);
          acc[ci][kt] = __builtin_amdgcn_mfma_f32_16x16x32_bf16(Al, Bh[kt], acc[ci][kt], 0, 0, 0);
          acc[ci][kt] = __builtin_amdgcn_mfma_f32_16x16x32_bf16(Ah, Bl[kt], acc[ci][kt], 0, 0, 0);
        }
      }
    }
    __syncthreads();
  }

  // ---- epilogue: vlad partials -> global atomics ----
  float* vb = vlad_acc + (size_t)n * K_ * C_;
#pragma unroll
  for (int ci = 0; ci < 2; ++ci) {
    const int c0 = (wv * 2 + ci) * 16 + lq * 4;
#pragma unroll
    for (int kt = 0; kt < 4; ++kt) {
      const int kc = kt * 16 + lm;
#pragma unroll
      for (int r = 0; r < 4; ++r)
        atomicAdd(vb + kc * C_ + c0 + r, acc[ci][kt][r]);
    }
  }

  // ---- epilogue: a-sum reduction (reuse sLog as scratch) ----
#pragma unroll
  for (int i = 0; i < 8; ++i) sLog[tid * 8 + i] = accA[i];
  __syncthreads();
  if (tid < K_) {
    float tsum = 0.f;
    for (int s8 = 0; s8 < 32; ++s8)
      tsum += sLog[(s8 * 8 + (tid & 7)) * 8 + (tid >> 3)];
    atomicAdd(asum_g + n * K_ + tid, tsum);
  }
}

// ---------------------------------------------------------------------------
// Kernel 2: subtract asum*centroid, intra-normalize over c, gnorm contribution
// ---------------------------------------------------------------------------
__global__ __launch_bounds__(128) void vlad_intra(
    float* __restrict__ vlad_acc, const float* __restrict__ asum_g,
    const float* __restrict__ cent, float* __restrict__ gnorm) {
  const int bid = blockIdx.x;
  const int n = bid >> 6, k = bid & 63;
  const int c = threadIdx.x;
  const size_t base = ((size_t)(n * K_ + k)) * C_;
  float a = asum_g[n * K_ + k];
  float v = vlad_acc[base + c] - a * cent[k * C_ + c];
  float ss = v * v;
  ss += __shfl_xor(ss, 1);  ss += __shfl_xor(ss, 2);  ss += __shfl_xor(ss, 4);
  ss += __shfl_xor(ss, 8);  ss += __shfl_xor(ss, 16); ss += __shfl_xor(ss, 32);
  __shared__ float red[2];
  if ((threadIdx.x & 63) == 0) red[threadIdx.x >> 6] = ss;
  __syncthreads();
  float total = red[0] + red[1];
  float nrm = fmaxf(sqrtf(total), EPS);
  vlad_acc[base + c] = v / nrm;
  if (threadIdx.x == 0) atomicAdd(gnorm + n, total / (nrm * nrm));
}

// ---------------------------------------------------------------------------
// Kernel 3: global L2 normalize per n
// ---------------------------------------------------------------------------
__global__ __launch_bounds__(256) void vlad_final(
    const float* __restrict__ vlad_acc, const float* __restrict__ gnorm,
    float* __restrict__ out) {
  const int idx = blockIdx.x * 256 + threadIdx.x;
  if (idx >= N_ * K_ * C_) return;
  float g = gnorm[idx >> 13];
  out[idx] = vlad_acc[idx] / fmaxf(sqrtf(g), EPS);
}

extern "C" void kernel_launch(void* const* d_in, const int* in_sizes, int n_in,
                              void* d_out, int out_size, void* d_ws, size_t ws_size,
                              hipStream_t stream) {
  const float* x    = (const float*)d_in[0];
  const float* w    = (const float*)d_in[1];
  const float* cent = (const float*)d_in[2];
  float* out = (float*)d_out;

  float* vlad_acc = (float*)d_ws;
  float* asum_g   = vlad_acc + N_ * K_ * C_;
  float* gnorm    = asum_g + N_ * K_;

  const size_t zero_bytes = (size_t)(N_ * K_ * C_ + N_ * K_ + N_) * sizeof(float);
  hipMemsetAsync(d_ws, 0, zero_bytes, stream);

  vlad_main<<<dim3(N_ * NCHUNK), dim3(256), 0, stream>>>(x, w, vlad_acc, asum_g);
  vlad_intra<<<dim3(N_ * K_), dim3(128), 0, stream>>>(vlad_acc, asum_g, cent, gnorm);
  vlad_final<<<dim3((N_ * K_ * C_ + 255) / 256), dim3(256), 0, stream>>>(vlad_acc, gnorm, out);
}

// Round 3
// 442.582 us; speedup vs baseline: 1.3892x; 1.1209x over previous
//
#include <hip/hip_runtime.h>
#include <hip/hip_bf16.h>

#define N_ 32
#define C_ 128
#define K_ 64
#define S_ 16384
#define TS 32                 // s-positions per inner tile
#define NCHUNK 32             // chunks per image -> 1024 blocks (4/CU)
#define CHUNK (S_/NCHUNK)     // 512
#define NITER (CHUNK/TS)      // 16
#define CP 136                // x^T LDS stride (bf16 elems)
#define LP 68                 // logits LDS stride (fp32)
#define SP 40                 // probs LDS stride (bf16 elems)
#define EPS 1e-12f

typedef __attribute__((ext_vector_type(8))) short short8;
typedef __attribute__((ext_vector_type(4))) float floatx4;

__device__ inline unsigned short bfraw(float v) {
  return __builtin_bit_cast(unsigned short, __float2bfloat16(v));
}
__device__ inline float bff(unsigned short u) {
  union { unsigned int i; float f; } c; c.i = ((unsigned int)u) << 16; return c.f;
}

// ---------------------------------------------------------------------------
// Fused: logits = W@x (MFMA split-bf16, 3-term) -> softmax over k ->
// vlad += a@x^T (MFMA, 2-term: x hi/lo x probs-hi). 1024 blocks x 256 thr.
// Prefetched staging; SLAB epilogue writes private per-block partials.
// ---------------------------------------------------------------------------
template <bool SLAB>
__global__ __launch_bounds__(256, 4) void vlad_main(
    const float* __restrict__ x, const float* __restrict__ w,
    float* __restrict__ vlad_out, float* __restrict__ asum_out) {
  __shared__ unsigned short sXTh[TS * CP];   // x^T tile hi [s][c]
  __shared__ unsigned short sXTl[TS * CP];   // x^T tile lo
  __shared__ float sLog[TS * LP];            // logits [s][kc]
  __shared__ unsigned short sPh[K_ * SP];    // probs hi [kc][s]

  const int tid = threadIdx.x;
  const int lane = tid & 63;
  const int wv = tid >> 6;
  const int n = blockIdx.x >> 5;
  const int chunk = blockIdx.x & 31;
  const int sbase = chunk * CHUNK;

  const int lm = lane & 15;
  const int lq = lane >> 4;
  const int kb = lq * 8;

  // GEMM1 B-fragments: W[kc][c] for kc-tile wv, in registers
  short8 Wh[4], Wl[4];
  {
    const float* wp = w + (wv * 16 + lm) * C_;
#pragma unroll
    for (int ks = 0; ks < 4; ++ks) {
      const float* p = wp + ks * 32 + kb;
      float4 a = *(const float4*)p;
      float4 b = *(const float4*)(p + 4);
      float e[8] = {a.x, a.y, a.z, a.w, b.x, b.y, b.z, b.w};
#pragma unroll
      for (int j = 0; j < 8; ++j) {
        unsigned short h = bfraw(e[j]);
        Wh[ks][j] = (short)h;
        Wl[ks][j] = (short)bfraw(e[j] - bff(h));
      }
    }
  }

  floatx4 acc[2][4];
#pragma unroll
  for (int i = 0; i < 2; ++i)
#pragma unroll
    for (int j = 0; j < 4; ++j) acc[i][j] = (floatx4){0.f, 0.f, 0.f, 0.f};
  float accA[8];
#pragma unroll
  for (int i = 0; i < 8; ++i) accA[i] = 0.f;

  const int cA = tid & 127, hA = tid >> 7;
  const float* xstg = x + ((size_t)n * C_ + cA) * S_ + sbase + hA * 16;
  const int sC = tid >> 3, octC = tid & 7;

  // prefetch tile 0
  float4 p0 = *(const float4*)(xstg + 0);
  float4 p1 = *(const float4*)(xstg + 4);
  float4 p2 = *(const float4*)(xstg + 8);
  float4 p3 = *(const float4*)(xstg + 12);

  for (int t = 0; t < NITER; ++t) {
    const int s0 = sbase + t * TS;

    // ---- Phase A: convert + store prefetched tile; issue next prefetch ----
    {
      float vv[16] = {p0.x,p0.y,p0.z,p0.w, p1.x,p1.y,p1.z,p1.w,
                      p2.x,p2.y,p2.z,p2.w, p3.x,p3.y,p3.z,p3.w};
      const int sb = hA * 16;
#pragma unroll
      for (int u = 0; u < 16; ++u) {
        unsigned short h = bfraw(vv[u]);
        sXTh[(sb + u) * CP + cA] = h;
        sXTl[(sb + u) * CP + cA] = bfraw(vv[u] - bff(h));
      }
    }
    if (t + 1 < NITER) {
      const float* p = xstg + (t + 1) * TS;
      p0 = *(const float4*)(p + 0);
      p1 = *(const float4*)(p + 4);
      p2 = *(const float4*)(p + 8);
      p3 = *(const float4*)(p + 12);
    }
    __syncthreads();

    // ---- Phase B: logits via MFMA (A = x^T LDS, B = W regs, 3-term) ----
#pragma unroll
    for (int st = 0; st < 2; ++st) {
      floatx4 D = {0.f, 0.f, 0.f, 0.f};
      const int srow = st * 16 + lm;
#pragma unroll
      for (int ks = 0; ks < 4; ++ks) {
        short8 Ah = *(const short8*)&sXTh[srow * CP + ks * 32 + kb];
        short8 Al = *(const short8*)&sXTl[srow * CP + ks * 32 + kb];
        D = __builtin_amdgcn_mfma_f32_16x16x32_bf16(Ah, Wh[ks], D, 0, 0, 0);
        D = __builtin_amdgcn_mfma_f32_16x16x32_bf16(Al, Wh[ks], D, 0, 0, 0);
        D = __builtin_amdgcn_mfma_f32_16x16x32_bf16(Ah, Wl[ks], D, 0, 0, 0);
      }
      const int sD = st * 16 + lq * 4;
      const int kcD = wv * 16 + lm;
#pragma unroll
      for (int r = 0; r < 4; ++r) sLog[(sD + r) * LP + kcD] = D[r];
    }
    __syncthreads();

    // ---- Phase C: issue D's x-loads (latency hidden by softmax), softmax ----
    short8 Ah2[2], Al2[2];
    {
      float4 xa[2], xb[2];
#pragma unroll
      for (int ci = 0; ci < 2; ++ci) {
        const int crow = (wv * 2 + ci) * 16 + lm;
        const float* xp = x + ((size_t)n * C_ + crow) * S_ + s0 + kb;
        xa[ci] = *(const float4*)xp;
        xb[ci] = *(const float4*)(xp + 4);
      }

      float e[8];
      float m = -1e30f;
#pragma unroll
      for (int i = 0; i < 8; ++i) {
        e[i] = sLog[sC * LP + octC + 8 * i];
        m = fmaxf(m, e[i]);
      }
      m = fmaxf(m, __shfl_xor(m, 1));
      m = fmaxf(m, __shfl_xor(m, 2));
      m = fmaxf(m, __shfl_xor(m, 4));
      float sum = 0.f;
#pragma unroll
      for (int i = 0; i < 8; ++i) { e[i] = __expf(e[i] - m); sum += e[i]; }
      sum += __shfl_xor(sum, 1);
      sum += __shfl_xor(sum, 2);
      sum += __shfl_xor(sum, 4);
      float inv = 1.f / sum;
#pragma unroll
      for (int i = 0; i < 8; ++i) {
        float pr = e[i] * inv;
        accA[i] += pr;
        sPh[(octC + 8 * i) * SP + sC] = bfraw(pr);
      }

#pragma unroll
      for (int ci = 0; ci < 2; ++ci) {
        float ee[8] = {xa[ci].x, xa[ci].y, xa[ci].z, xa[ci].w,
                       xb[ci].x, xb[ci].y, xb[ci].z, xb[ci].w};
#pragma unroll
        for (int j = 0; j < 8; ++j) {
          unsigned short h = bfraw(ee[j]);
          Ah2[ci][j] = (short)h;
          Al2[ci][j] = (short)bfraw(ee[j] - bff(h));
        }
      }
    }
    __syncthreads();

    // ---- Phase D: vlad^T += x (hi/lo) x probs-hi ----
    {
      short8 Bh[4];
#pragma unroll
      for (int kt = 0; kt < 4; ++kt)
        Bh[kt] = *(const short8*)&sPh[(kt * 16 + lm) * SP + kb];
#pragma unroll
      for (int ci = 0; ci < 2; ++ci) {
#pragma unroll
        for (int kt = 0; kt < 4; ++kt) {
          acc[ci][kt] = __builtin_amdgcn_mfma_f32_16x16x32_bf16(Ah2[ci], Bh[kt], acc[ci][kt], 0, 0, 0);
          acc[ci][kt] = __builtin_amdgcn_mfma_f32_16x16x32_bf16(Al2[ci], Bh[kt], acc[ci][kt], 0, 0, 0);
        }
      }
    }
    __syncthreads();
  }

  // ---- epilogue: vlad partials ----
  float* vb = vlad_out + (SLAB ? (size_t)blockIdx.x : (size_t)n) * (K_ * C_);
#pragma unroll
  for (int ci = 0; ci < 2; ++ci) {
    const int c0 = (wv * 2 + ci) * 16 + lq * 4;
#pragma unroll
    for (int kt = 0; kt < 4; ++kt) {
      const int kc = kt * 16 + lm;
      if (SLAB) {
        *(floatx4*)(vb + kc * C_ + c0) = acc[ci][kt];
      } else {
#pragma unroll
        for (int r = 0; r < 4; ++r)
          atomicAdd(vb + kc * C_ + c0 + r, acc[ci][kt][r]);
      }
    }
  }

  // ---- epilogue: a-sum reduction (sLog as scratch) ----
#pragma unroll
  for (int i = 0; i < 8; ++i) sLog[tid * 8 + i] = accA[i];
  __syncthreads();
  if (tid < K_) {
    float tsum = 0.f;
    for (int s8 = 0; s8 < 32; ++s8)
      tsum += sLog[(s8 * 8 + (tid & 7)) * 8 + (tid >> 3)];
    if (SLAB) asum_out[(size_t)blockIdx.x * K_ + tid] = tsum;
    else atomicAdd(asum_out + n * K_ + tid, tsum);
  }
}

// ---------------------------------------------------------------------------
// Kernel 2: reduce slabs (if SLAB), subtract asum*centroid, intra-normalize,
// accumulate global-norm contribution. Writes vlad_norm.
// ---------------------------------------------------------------------------
template <bool SLAB>
__global__ __launch_bounds__(128) void vlad_intra(
    const float* __restrict__ vlad_in, const float* __restrict__ asum_in,
    const float* __restrict__ cent, float* __restrict__ vlad_norm,
    float* __restrict__ gnorm) {
  const int bid = blockIdx.x;
  const int n = bid >> 6, k = bid & 63;
  const int c = threadIdx.x;

  float v, a;
  if (SLAB) {
    v = 0.f; a = 0.f;
#pragma unroll 4
    for (int ch = 0; ch < NCHUNK; ++ch) {
      v += vlad_in[((size_t)(n * NCHUNK + ch) * K_ + k) * C_ + c];
      a += asum_in[(n * NCHUNK + ch) * K_ + k];  // broadcast load
    }
  } else {
    v = vlad_in[((size_t)(n * K_ + k)) * C_ + c];
    a = asum_in[n * K_ + k];
  }
  v -= a * cent[k * C_ + c];

  float ss = v * v;
  ss += __shfl_xor(ss, 1);  ss += __shfl_xor(ss, 2);  ss += __shfl_xor(ss, 4);
  ss += __shfl_xor(ss, 8);  ss += __shfl_xor(ss, 16); ss += __shfl_xor(ss, 32);
  __shared__ float red[2];
  if ((threadIdx.x & 63) == 0) red[threadIdx.x >> 6] = ss;
  __syncthreads();
  float total = red[0] + red[1];
  float nrm = fmaxf(sqrtf(total), EPS);
  vlad_norm[((size_t)(n * K_ + k)) * C_ + c] = v / nrm;
  if (threadIdx.x == 0) atomicAdd(gnorm + n, total / (nrm * nrm));
}

// ---------------------------------------------------------------------------
// Kernel 3: global L2 normalize per n
// ---------------------------------------------------------------------------
__global__ __launch_bounds__(256) void vlad_final(
    const float* __restrict__ vlad_norm, const float* __restrict__ gnorm,
    float* __restrict__ out) {
  const int idx = blockIdx.x * 256 + threadIdx.x;
  if (idx >= N_ * K_ * C_) return;
  float g = gnorm[idx >> 13];
  out[idx] = vlad_norm[idx] / fmaxf(sqrtf(g), EPS);
}

extern "C" void kernel_launch(void* const* d_in, const int* in_sizes, int n_in,
                              void* d_out, int out_size, void* d_ws, size_t ws_size,
                              hipStream_t stream) {
  const float* x    = (const float*)d_in[0];
  const float* w    = (const float*)d_in[1];
  const float* cent = (const float*)d_in[2];
  float* out = (float*)d_out;

  const int nblk = N_ * NCHUNK;  // 1024
  const size_t slab_f  = (size_t)nblk * K_ * C_;   // 8,388,608 floats
  const size_t asum_f  = (size_t)nblk * K_;        // 65,536
  const size_t norm_f  = (size_t)N_ * K_ * C_;     // 262,144
  const size_t need = (slab_f + asum_f + norm_f + N_) * sizeof(float);

  if (ws_size >= need) {
    float* slab   = (float*)d_ws;
    float* asums  = slab + slab_f;
    float* vnorm  = asums + asum_f;
    float* gnorm  = vnorm + norm_f;
    hipMemsetAsync(gnorm, 0, N_ * sizeof(float), stream);
    vlad_main<true><<<dim3(nblk), dim3(256), 0, stream>>>(x, w, slab, asums);
    vlad_intra<true><<<dim3(N_ * K_), dim3(128), 0, stream>>>(slab, asums, cent, vnorm, gnorm);
    vlad_final<<<dim3((N_ * K_ * C_ + 255) / 256), dim3(256), 0, stream>>>(vnorm, gnorm, out);
  } else {
    float* vlad_acc = (float*)d_ws;                 // N*K*C
    float* asum_g   = vlad_acc + norm_f;            // N*K
    float* gnorm    = asum_g + N_ * K_;             // N
    hipMemsetAsync(d_ws, 0, (norm_f + N_ * K_ + N_) * sizeof(float), stream);
    vlad_main<false><<<dim3(nblk), dim3(256), 0, stream>>>(x, w, vlad_acc, asum_g);
    vlad_intra<false><<<dim3(N_ * K_), dim3(128), 0, stream>>>(vlad_acc, asum_g, cent, vlad_acc, gnorm);
    vlad_final<<<dim3((N_ * K_ * C_ + 255) / 256), dim3(256), 0, stream>>>(vlad_acc, gnorm, out);
  }
}

// Round 4
// 414.781 us; speedup vs baseline: 1.4823x; 1.0670x over previous
//
#include <hip/hip_runtime.h>

#define N_ 32
#define C_ 128
#define K_ 64
#define S_ 16384
#define TS 64                 // s-positions per tile
#define NBPN 24               // blocks per image (768 total = 3/CU exactly)
#define NTILES (S_/TS)        // 256 tiles per image
#define NBLK (N_*NBPN)
#define XS 136                // sXT stride (halfs, 272B = 16B-mult)
#define WS 136                // sW stride
#define PS 72                 // sP stride (144B = 16B-mult)
#define EPS 1e-12f

typedef __attribute__((ext_vector_type(8))) _Float16 half8;
typedef __attribute__((ext_vector_type(4))) _Float16 half4;
typedef __attribute__((ext_vector_type(4))) float floatx4;

// XOR-swizzle 32B (16-half) blocks within a row to decorrelate bank patterns.
__device__ __forceinline__ int swz(int row, int c) {
  return (((c >> 4) ^ (row & 7)) << 4) | (c & 15);
}

// ---------------------------------------------------------------------------
// Fused: logits = W@x (fp16 MFMA) -> in-register softmax over all 64 kc
// (each wave owns a 16-s subtile => shfl-only reduction) -> vlad += a@x^T.
// 768 blocks x 256 threads, 2 barriers per 64-s tile.
// ---------------------------------------------------------------------------
template <bool SLAB>
__global__ __launch_bounds__(256, 4) void vlad_main(
    const float* __restrict__ x, const float* __restrict__ w,
    float* __restrict__ vlad_out, float* __restrict__ asum_out) {
  __shared__ _Float16 sXT[TS * XS];   // x^T tile [s][c] fp16, swizzled
  __shared__ _Float16 sW[K_ * WS];    // conv_w [kc][c] fp16, swizzled
  __shared__ _Float16 sP[K_ * PS];    // probs [kc][s] fp16
  __shared__ float sRed[4 * K_];      // asum cross-wave scratch

  const int tid = threadIdx.x;
  const int lane = tid & 63;
  const int wv = tid >> 6;
  const int lm = lane & 15;
  const int quad = lane >> 4;

  const int bid = blockIdx.x;
  const int n = bid / NBPN;
  const int j = bid % NBPN;
  const int ts = (j * NTILES) / NBPN;
  const int te = ((j + 1) * NTILES) / NBPN;

  // W -> LDS once per block
  for (int idx = tid; idx < K_ * C_; idx += 256) {
    int kc = idx >> 7, c = idx & 127;
    sW[kc * WS + swz(kc, c)] = (_Float16)w[idx];
  }

  floatx4 acc[2][4];
#pragma unroll
  for (int i = 0; i < 2; ++i)
#pragma unroll
    for (int k = 0; k < 4; ++k) acc[i][k] = (floatx4){0.f, 0.f, 0.f, 0.f};
  float accA[4] = {0.f, 0.f, 0.f, 0.f};

  const int cw = tid & 15;      // staging: c-rows 8*cw .. 8*cw+7
  const int sq = tid >> 4;      // staging: s = 4*sq + u
  const float* xn = x + (size_t)n * C_ * S_;

  // prefetch tile ts
  float4 pf[8];
  {
    const float* p = xn + (size_t)(8 * cw) * S_ + ts * TS + 4 * sq;
#pragma unroll
    for (int r = 0; r < 8; ++r) pf[r] = *(const float4*)(p + (size_t)r * S_);
  }

  __syncthreads();  // sW ready

  for (int t = ts; t < te; ++t) {
    const int s0 = t * TS;

    // ---- A: store staged tile (in-register transpose, fp16, b128 writes) ----
#pragma unroll
    for (int u = 0; u < 4; ++u) {
      const int s = 4 * sq + u;
      half8 hv;
#pragma unroll
      for (int r = 0; r < 8; ++r) {
        float f = (u == 0) ? pf[r].x : (u == 1) ? pf[r].y : (u == 2) ? pf[r].z : pf[r].w;
        hv[r] = (_Float16)f;
      }
      *(half8*)&sXT[s * XS + swz(s, 8 * cw)] = hv;
    }
    __syncthreads();  // post-A (sXT ready)

    // ---- B: issue GEMM2 x-loads (first half), then GEMM1 MFMAs ----
    float4 gxa[2][2];
#pragma unroll
    for (int ci = 0; ci < 2; ++ci) {
      const float* p = xn + (size_t)((2 * wv + ci) * 16 + lm) * S_ + s0 + quad * 8;
      gxa[ci][0] = *(const float4*)p;
      gxa[ci][1] = *(const float4*)(p + 4);
    }

    floatx4 D[4];
#pragma unroll
    for (int k = 0; k < 4; ++k) D[k] = (floatx4){0.f, 0.f, 0.f, 0.f};
    const int srow = wv * 16 + lm;
#pragma unroll
    for (int ks = 0; ks < 4; ++ks) {
      half8 Af = *(const half8*)&sXT[srow * XS + swz(srow, ks * 32 + quad * 8)];
#pragma unroll
      for (int kt = 0; kt < 4; ++kt) {
        const int krow = kt * 16 + lm;
        half8 Wf = *(const half8*)&sW[krow * WS + swz(krow, ks * 32 + quad * 8)];
        D[kt] = __builtin_amdgcn_mfma_f32_16x16x32_f16(Af, Wf, D[kt], 0, 0, 0);
      }
    }

    // ---- C: in-register softmax over all 64 kc per s-row (shfl over 16-group) ----
#pragma unroll
    for (int r = 0; r < 4; ++r) {
      float m = fmaxf(fmaxf(D[0][r], D[1][r]), fmaxf(D[2][r], D[3][r]));
      m = fmaxf(m, __shfl_xor(m, 1));
      m = fmaxf(m, __shfl_xor(m, 2));
      m = fmaxf(m, __shfl_xor(m, 4));
      m = fmaxf(m, __shfl_xor(m, 8));
      float e0 = __expf(D[0][r] - m), e1 = __expf(D[1][r] - m),
            e2 = __expf(D[2][r] - m), e3 = __expf(D[3][r] - m);
      float sum = e0 + e1 + e2 + e3;
      sum += __shfl_xor(sum, 1);
      sum += __shfl_xor(sum, 2);
      sum += __shfl_xor(sum, 4);
      sum += __shfl_xor(sum, 8);
      float inv = 1.f / sum;
      D[0][r] = e0 * inv; D[1][r] = e1 * inv;
      D[2][r] = e2 * inv; D[3][r] = e3 * inv;
    }
#pragma unroll
    for (int kt = 0; kt < 4; ++kt) {
      accA[kt] += D[kt][0] + D[kt][1] + D[kt][2] + D[kt][3];
      half4 hp = {(_Float16)D[kt][0], (_Float16)D[kt][1],
                  (_Float16)D[kt][2], (_Float16)D[kt][3]};
      *(half4*)&sP[(kt * 16 + lm) * PS + wv * 16 + quad * 4] = hp;
    }
    // issue GEMM2 x-loads (second half) — latency hides under barrier + ks2=0
    float4 gxb[2][2];
#pragma unroll
    for (int ci = 0; ci < 2; ++ci) {
      const float* p = xn + (size_t)((2 * wv + ci) * 16 + lm) * S_ + s0 + 32 + quad * 8;
      gxb[ci][0] = *(const float4*)p;
      gxb[ci][1] = *(const float4*)(p + 4);
    }
    __syncthreads();  // post-C (sP ready)

    // ---- D: GEMM2, s-half 0 ----
    {
      half8 Bp[4];
#pragma unroll
      for (int kt = 0; kt < 4; ++kt)
        Bp[kt] = *(const half8*)&sP[(kt * 16 + lm) * PS + quad * 8];
#pragma unroll
      for (int ci = 0; ci < 2; ++ci) {
        half8 Ax = {(_Float16)gxa[ci][0].x, (_Float16)gxa[ci][0].y,
                    (_Float16)gxa[ci][0].z, (_Float16)gxa[ci][0].w,
                    (_Float16)gxa[ci][1].x, (_Float16)gxa[ci][1].y,
                    (_Float16)gxa[ci][1].z, (_Float16)gxa[ci][1].w};
#pragma unroll
        for (int kt = 0; kt < 4; ++kt)
          acc[ci][kt] = __builtin_amdgcn_mfma_f32_16x16x32_f16(Ax, Bp[kt], acc[ci][kt], 0, 0, 0);
      }
    }
    // prefetch next tile (overlaps s-half-1 MFMAs)
    if (t + 1 < te) {
      const float* p = xn + (size_t)(8 * cw) * S_ + (t + 1) * TS + 4 * sq;
#pragma unroll
      for (int r = 0; r < 8; ++r) pf[r] = *(const float4*)(p + (size_t)r * S_);
    }
    // ---- D: GEMM2, s-half 1 ----
    {
      half8 Bp[4];
#pragma unroll
      for (int kt = 0; kt < 4; ++kt)
        Bp[kt] = *(const half8*)&sP[(kt * 16 + lm) * PS + 32 + quad * 8];
#pragma unroll
      for (int ci = 0; ci < 2; ++ci) {
        half8 Ax = {(_Float16)gxb[ci][0].x, (_Float16)gxb[ci][0].y,
                    (_Float16)gxb[ci][0].z, (_Float16)gxb[ci][0].w,
                    (_Float16)gxb[ci][1].x, (_Float16)gxb[ci][1].y,
                    (_Float16)gxb[ci][1].z, (_Float16)gxb[ci][1].w};
#pragma unroll
        for (int kt = 0; kt < 4; ++kt)
          acc[ci][kt] = __builtin_amdgcn_mfma_f32_16x16x32_f16(Ax, Bp[kt], acc[ci][kt], 0, 0, 0);
      }
    }
  }

  // ---- epilogue: vlad partials (D layout: kc = kt*16+lm, c = (2wv+ci)*16+quad*4+r) ----
  float* vb = vlad_out + (SLAB ? (size_t)bid : (size_t)n) * (K_ * C_);
#pragma unroll
  for (int ci = 0; ci < 2; ++ci) {
    const int c0 = (2 * wv + ci) * 16 + quad * 4;
#pragma unroll
    for (int kt = 0; kt < 4; ++kt) {
      const int kc = kt * 16 + lm;
      if (SLAB) {
        *(floatx4*)(vb + kc * C_ + c0) = acc[ci][kt];
      } else {
#pragma unroll
        for (int r = 0; r < 4; ++r)
          atomicAdd(vb + kc * C_ + c0 + r, acc[ci][kt][r]);
      }
    }
  }

  // ---- epilogue: asum (reduce quads via shfl, waves via sRed) ----
#pragma unroll
  for (int kt = 0; kt < 4; ++kt) {
    float v = accA[kt];
    v += __shfl_xor(v, 16);
    v += __shfl_xor(v, 32);
    if (quad == 0) sRed[wv * K_ + kt * 16 + lm] = v;
  }
  __syncthreads();
  if (tid < K_) {
    float s = sRed[tid] + sRed[K_ + tid] + sRed[2 * K_ + tid] + sRed[3 * K_ + tid];
    if (SLAB) asum_out[(size_t)bid * K_ + tid] = s;
    else atomicAdd(asum_out + n * K_ + tid, s);
  }
}

// ---------------------------------------------------------------------------
// Kernel 2: reduce slabs, subtract asum*centroid, intra-normalize, gnorm
// ---------------------------------------------------------------------------
template <bool SLAB>
__global__ __launch_bounds__(128) void vlad_intra(
    const float* __restrict__ vlad_in, const float* __restrict__ asum_in,
    const float* __restrict__ cent, float* __restrict__ vlad_norm,
    float* __restrict__ gnorm) {
  const int bid = blockIdx.x;
  const int n = bid >> 6, k = bid & 63;
  const int c = threadIdx.x;

  float v, a;
  if (SLAB) {
    v = 0.f; a = 0.f;
#pragma unroll 4
    for (int ch = 0; ch < NBPN; ++ch) {
      v += vlad_in[((size_t)(n * NBPN + ch) * K_ + k) * C_ + c];
      a += asum_in[(n * NBPN + ch) * K_ + k];
    }
  } else {
    v = vlad_in[((size_t)(n * K_ + k)) * C_ + c];
    a = asum_in[n * K_ + k];
  }
  v -= a * cent[k * C_ + c];

  float ss = v * v;
  ss += __shfl_xor(ss, 1);  ss += __shfl_xor(ss, 2);  ss += __shfl_xor(ss, 4);
  ss += __shfl_xor(ss, 8);  ss += __shfl_xor(ss, 16); ss += __shfl_xor(ss, 32);
  __shared__ float red[2];
  if ((threadIdx.x & 63) == 0) red[threadIdx.x >> 6] = ss;
  __syncthreads();
  float total = red[0] + red[1];
  float nrm = fmaxf(sqrtf(total), EPS);
  vlad_norm[((size_t)(n * K_ + k)) * C_ + c] = v / nrm;
  if (threadIdx.x == 0) atomicAdd(gnorm + n, total / (nrm * nrm));
}

// ---------------------------------------------------------------------------
// Kernel 3: global L2 normalize per n
// ---------------------------------------------------------------------------
__global__ __launch_bounds__(256) void vlad_final(
    const float* __restrict__ vlad_norm, const float* __restrict__ gnorm,
    float* __restrict__ out) {
  const int idx = blockIdx.x * 256 + threadIdx.x;
  if (idx >= N_ * K_ * C_) return;
  float g = gnorm[idx >> 13];
  out[idx] = vlad_norm[idx] / fmaxf(sqrtf(g), EPS);
}

extern "C" void kernel_launch(void* const* d_in, const int* in_sizes, int n_in,
                              void* d_out, int out_size, void* d_ws, size_t ws_size,
                              hipStream_t stream) {
  const float* x    = (const float*)d_in[0];
  const float* w    = (const float*)d_in[1];
  const float* cent = (const float*)d_in[2];
  float* out = (float*)d_out;

  const size_t slab_f = (size_t)NBLK * K_ * C_;    // 6,291,456 floats (25.2 MB)
  const size_t asum_f = (size_t)NBLK * K_;         // 49,152
  const size_t norm_f = (size_t)N_ * K_ * C_;      // 262,144
  const size_t need = (slab_f + asum_f + norm_f + N_) * sizeof(float);

  if (ws_size >= need) {
    float* slab  = (float*)d_ws;
    float* asums = slab + slab_f;
    float* vnorm = asums + asum_f;
    float* gnorm = vnorm + norm_f;
    hipMemsetAsync(gnorm, 0, N_ * sizeof(float), stream);
    vlad_main<true><<<dim3(NBLK), dim3(256), 0, stream>>>(x, w, slab, asums);
    vlad_intra<true><<<dim3(N_ * K_), dim3(128), 0, stream>>>(slab, asums, cent, vnorm, gnorm);
    vlad_final<<<dim3((N_ * K_ * C_ + 255) / 256), dim3(256), 0, stream>>>(vnorm, gnorm, out);
  } else {
    float* vlad_acc = (float*)d_ws;
    float* asum_g   = vlad_acc + norm_f;
    float* gnorm    = asum_g + N_ * K_;
    hipMemsetAsync(d_ws, 0, (norm_f + N_ * K_ + N_) * sizeof(float), stream);
    vlad_main<false><<<dim3(NBLK), dim3(256), 0, stream>>>(x, w, vlad_acc, asum_g);
    vlad_intra<false><<<dim3(N_ * K_), dim3(128), 0, stream>>>(vlad_acc, asum_g, cent, vlad_acc, gnorm);
    vlad_final<<<dim3((N_ * K_ * C_ + 255) / 256), dim3(256), 0, stream>>>(vlad_acc, gnorm, out);
  }
}